// Round 12
// baseline (258.184 us; speedup 1.0000x reference)
//
#include <hip/hip_runtime.h>

typedef unsigned short u16;
typedef __bf16 bf16_t;
typedef bf16_t bf16x8 __attribute__((ext_vector_type(8)));
typedef float floatx4 __attribute__((ext_vector_type(4)));

static constexpr float kScale = 0.014731391274719741f;    // 1/sqrt(512*9)
static constexpr float kScale2 = 2.1701388888888894e-4f;  // 1/(512*9)
static constexpr float kLinScale = 0.044194173824159216f; // 1/sqrt(512)

__device__ __forceinline__ u16 f2bf(float f) {
  unsigned u = __float_as_uint(f);
  u += 0x7FFFu + ((u >> 16) & 1u);
  return (u16)(u >> 16);
}

// async 16B global->LDS; LDS dst semantics: wave-uniform base + lane*16
#define GLD16(g, l)                                                        \
  __builtin_amdgcn_global_load_lds(                                        \
      (const __attribute__((address_space(1))) unsigned int*)(g),          \
      (__attribute__((address_space(3))) unsigned int*)(l), 16, 0, 0)

// ---------------------------------------------------------------------------
// Fused prep: blocks [0,1024): s[b,c] = style.modw^T*lin + bias
//             blocks [1024,2048): ssq[o,c] = sum_tap w^2
__global__ __launch_bounds__(256) void k_prep1(const float* __restrict__ style,
                                               const float* __restrict__ modw,
                                               const float* __restrict__ modb,
                                               const float* __restrict__ weight,
                                               float* __restrict__ s_buf,
                                               float* __restrict__ ssq) {
  int tid = threadIdx.x;
  if (blockIdx.x < 1024) {
    int lane = tid & 63, wv = tid >> 6;
    int idx = blockIdx.x * 4 + wv; // [0,4096)
    int b = idx >> 9, c = idx & 511;
    const float* st = style + b * 512;
    const float* mw = modw + (size_t)c * 512;
    float s = 0.f;
#pragma unroll
    for (int i = 0; i < 8; ++i) s += st[lane + i * 64] * mw[lane + i * 64];
#pragma unroll
    for (int off = 32; off; off >>= 1) s += __shfl_xor(s, off);
    if (lane == 0) s_buf[idx] = s * kLinScale + modb[c];
  } else {
    int e = (blockIdx.x - 1024) * 256 + tid; // [0, 262144)
    const float* wp = weight + (size_t)e * 9;
    float ss = 0.f;
#pragma unroll
    for (int t = 0; t < 9; ++t) ss += wp[t] * wp[t];
    ssq[e] = ss;
  }
}

// ---------------------------------------------------------------------------
// Fused stage 2 (one launch) — R10 version (scalar transpose: verified
// conflict-free LDS access; R11's "vectorized" variant added even-bank
// collisions at stride-136B and regressed ~4 us. Reverted.):
//   blocks [0,4096):      NCHW f32 -> NHWC bf16 transpose with modulation
//   blocks [4096,4608):   weight fragment repack (batch-independent)
//   blocks [4608,5632):   demod[b,o] = rsqrt(kScale^2*sum ssq*s^2 + eps)
__global__ __launch_bounds__(256) void k_fused2(const float* __restrict__ in,
                                                const float* __restrict__ s_buf,
                                                const float* __restrict__ weight,
                                                const float* __restrict__ ssq,
                                                unsigned* __restrict__ in_t32,
                                                unsigned* __restrict__ wt32,
                                                float* __restrict__ demod_buf) {
  __shared__ char shm[9216];
  int tid = threadIdx.x;
  int bid = blockIdx.x;
  if (bid < 4096) {
    // ---- transpose: bid = c0g + 8*y + 512*b ----
    u16* tile = (u16*)shm; // [64*65] u16 = 8320 B
    int c0 = (bid & 7) * 64, y = (bid >> 3) & 63, b = bid >> 9;
    const float* src = in + ((size_t)(b * 512 + c0) * 4096) + y * 64;
    const float* srow = s_buf + b * 512 + c0;
#pragma unroll
    for (int it = 0; it < 16; ++it) {
      int idx = it * 256 + tid;
      int cl = idx >> 6, x = idx & 63;
      tile[cl * 65 + x] = f2bf(src[(size_t)cl * 4096 + x] * srow[cl]);
    }
    __syncthreads();
    unsigned* dst = in_t32 + ((size_t)(b * 64 + y) * 64) * 256 + (c0 >> 1);
#pragma unroll
    for (int it = 0; it < 8; ++it) {
      int flat = it * 256 + tid; // [0,2048)
      int cl2 = flat & 31, x = flat >> 5;
      unsigned lo = tile[(2 * cl2) * 65 + x];
      unsigned hi = tile[(2 * cl2 + 1) * 65 + x];
      dst[(size_t)x * 256 + cl2] = lo | (hi << 16);
    }
  } else if (bid < 4608) {
    // ---- wfrag: w = bid-4096; ct = w&15, ot = w>>4 ----
    u16(*tiles)[512] = (u16(*)[512])shm; // [9][512] u16 = 9216 B
    int w = bid - 4096;
    int ct = w & 15, ot = w >> 4;
    int o0 = ot * 16, c0 = ct * 32;
#pragma unroll
    for (int i = 0; i < 18; ++i) {
      int flat = i * 256 + tid;       // [0,4608) = o_l*288 + c_l*9 + tap
      int t9 = flat / 9;
      int tap = flat - t9 * 9;
      int o_l = t9 >> 5, c_l = t9 & 31;
      float wt = weight[((size_t)(o0 + o_l) * 512 + c0 + c_l) * 9 + tap];
      int pos = ((o_l + ((c_l >> 3) << 4)) << 3) + (c_l & 7);
      tiles[tap][pos] = f2bf(wt * kScale);
    }
    __syncthreads();
    const unsigned* tl = (const unsigned*)tiles;
#pragma unroll
    for (int tap = 0; tap < 9; ++tap)
      wt32[(size_t)((tap * 16 + ct) * 32 + ot) * 256 + tid] = tl[tap * 256 + tid];
  } else {
    // ---- demod: idx = (bid-4608)*4 + wave ----
    int lane = tid & 63, wv = tid >> 6;
    int idx = (bid - 4608) * 4 + wv; // [0,4096)
    int b = idx >> 9, o = idx & 511;
    const float* sq = ssq + (size_t)o * 512;
    const float* srow = s_buf + b * 512;
    float ss = 0.f;
#pragma unroll
    for (int i = 0; i < 8; ++i) {
      float s = srow[lane + i * 64];
      ss += sq[lane + i * 64] * s * s;
    }
#pragma unroll
    for (int off = 32; off; off >>= 1) ss += __shfl_xor(ss, off);
    if (lane == 0) demod_buf[idx] = rsqrtf(ss * kScale2 + 1e-8f);
  }
}

// ---------------------------------------------------------------------------
// Implicit-GEMM conv — R10 champion structure (b-major XCD swizzle restored;
// R11's mt-major regressed: FETCH +10 MB, conv +2 us). ONE change vs R10:
// s_setprio removed from the MFMA cluster — T5 evidence (m190) shows setprio
// is null-to-negative on lockstep (non-phase-split) GEMM structures like
// this barrier-free t-loop. Single-variable A/B on the champion.
// K=64 per t-step, double-buffered 64-ch B cells, proven 64B-cell 8-slot
// swizzle (conflicts = 0), depth-1 A/B register rings, counted vmcnt(8)
// barrier, XCD swizzle lin&7 = batch.
__global__ __launch_bounds__(256, 2) void k_conv(const u16* __restrict__ in_t,
                                                 const u16* __restrict__ w_t,
                                                 const float* __restrict__ demod_buf,
                                                 float* __restrict__ out) {
  __shared__ char smem[67584]; // 2 buffers x (4 rows x 66 cells x 128 B)
  const int tid = threadIdx.x;
  const int lane = tid & 63;
  const int wv = tid >> 6;
  const int wm = wv >> 1, wn = wv & 1;
  const int quad = lane >> 4, m16 = lane & 15;
  const int lin = blockIdx.x + 32 * blockIdx.y + 128 * blockIdx.z; // [0,1024)
  const int b = lin & 7;
  const int r_ = lin >> 3;   // [0,128)
  const int nt = r_ & 31;
  const int mt = r_ >> 5;    // [0,4)
  const int y0 = nt * 2;

  floatx4 acc[4][4];
#pragma unroll
  for (int i = 0; i < 4; ++i)
#pragma unroll
    for (int j = 0; j < 4; ++j) acc[i][j] = (floatx4){0.f, 0.f, 0.f, 0.f};

  // per-lane A base (u16); A frag ms of (tap, ct32) at
  // abase + ((tap*16 + ct32)<<14) + ms*512, ct32 = 2*ct' + kh
  const u16* abase = w_t + mt * 4096 + wm * 2048 + lane * 8;

  // B stage source: thread covers slot chunk of cell xs (h=0: x 0..31;
  // h=1 adds +16384 u16 = +32 cells). Inverse swizzle on the source.
  const int xs = tid >> 3, qs = tid & 7;
  const int cch = qs ^ (xs & 7); // global 8-ch chunk stored at slot qs
  const u16* gB[4];
  bool rok[4];
#pragma unroll
  for (int r = 0; r < 4; ++r) {
    int y = y0 - 1 + r;
    rok[r] = (unsigned)y < 64u; // block-uniform
    gB[r] = in_t + (((size_t)(b * 64 + (rok[r] ? y : 0)) * 64 + xs) * 512 + cch * 8);
  }

  // B read bases, one per (dx, kh). row=(wn+dy):
  // addr = row*8448 + (sx+1)*128 + ((kh*4+quad)^(sx&7))*16,
  // sx = ns*16+m16+dx-1; ns-step = +2048 (slot invariant), dy-step = +8448.
  char* bA[6];
#pragma unroll
  for (int dx = 0; dx < 3; ++dx) {
    const int sx0 = m16 + dx - 1;
#pragma unroll
    for (int kh = 0; kh < 2; ++kh)
      bA[dx * 2 + kh] = smem + wn * 8448 + (sx0 + 1) * 128 +
                        (((kh * 4 + quad) ^ (sx0 & 7)) << 4);
  }

  bf16x8 aR[2][2][4];
  bf16x8 bv[2][2][4];

#define LOAD_BV(si, bufimm, t_)                                              \
  {                                                                          \
    const int dy_ = (t_) / 3, dx_ = (t_) % 3;                                \
    _Pragma("unroll") for (int kh = 0; kh < 2; ++kh)                         \
      _Pragma("unroll") for (int ns = 0; ns < 4; ++ns)                       \
        bv[si][kh][ns] = *(const bf16x8*)(bA[dx_ * 2 + kh] + (bufimm) +      \
                                          dy_ * 8448 + ns * 2048);           \
  }

#define STAGE_B(bufimm)                                                      \
  {                                                                          \
    _Pragma("unroll") for (int r = 0; r < 4; ++r)                            \
      if (rok[r]) {                                                          \
        GLD16(gB[r], smem + (bufimm) + r * 8448 + 128 + wv * 1024);          \
        GLD16(gB[r] + 16384,                                                 \
              smem + (bufimm) + r * 8448 + 128 + 4096 + wv * 1024);          \
      }                                                                      \
  }

#define LOAD_A2(si, tp_, ctp_)                                               \
  {                                                                          \
    _Pragma("unroll") for (int kh = 0; kh < 2; ++kh) {                       \
      const u16* ap_ =                                                       \
          abase + ((size_t)((tp_)*16 + 2 * (ctp_) + kh) << 14);              \
      _Pragma("unroll") for (int ms = 0; ms < 4; ++ms)                       \
        aR[si][kh][ms] = *(const bf16x8*)(ap_ + ms * 512);                   \
    }                                                                        \
  }

// one ct' (64 channels): 9 tap-steps of 32 MFMA; A+B frag prefetch depth 1;
// stage(ct'+1) in flight across the whole t-loop, drained by vmcnt(8).
#define CT_BODY(ctv, par, CURIMM, NXTIMM)                                    \
  {                                                                          \
    LOAD_BV(par, CURIMM, 0);                                                 \
    if ((ctv) + 1 < 8) {                                                     \
      _Pragma("unroll") for (int r = 0; r < 4; ++r) gB[r] += 64;             \
      STAGE_B(NXTIMM);                                                       \
    }                                                                        \
    _Pragma("unroll") for (int t = 0; t < 9; ++t) {                          \
      const int icur = (t + (par)) & 1;                                      \
      const int inxt = icur ^ 1;                                             \
      const int tp = t < 8 ? t + 1 : 0;                                      \
      const int ctp = t < 8 ? (ctv) : (ctv) + 1;                             \
      LOAD_A2(inxt, tp, ctp);                                                \
      if (t < 8) { LOAD_BV(inxt, CURIMM, t + 1); }                           \
      _Pragma("unroll") for (int kh = 0; kh < 2; ++kh)                       \
        _Pragma("unroll") for (int ns = 0; ns < 4; ++ns)                     \
          _Pragma("unroll") for (int ms = 0; ms < 4; ++ms)                   \
            acc[ms][ns] = __builtin_amdgcn_mfma_f32_16x16x32_bf16(           \
                aR[icur][kh][ms], bv[icur][kh][ns], acc[ms][ns], 0, 0, 0);   \
    }                                                                        \
    asm volatile("s_waitcnt vmcnt(8)" ::: "memory");                         \
    __builtin_amdgcn_s_barrier();                                            \
  }

  // ---- prologue: zero LDS (pads + OOB rows), stage ct'=0, load A(0, 0|1) --
  {
    const uint4 z = make_uint4(0u, 0u, 0u, 0u);
    for (int i = tid; i < 4224; i += 256) ((uint4*)smem)[i] = z;
  }
  __syncthreads();
  STAGE_B(0);
  __syncthreads(); // drains stage(0) + makes zeros visible
  LOAD_A2(0, 0, 0);

  for (int ct = 0; ct < 8; ct += 2) {
    CT_BODY(ct, 0, 0, 33792);
    CT_BODY(ct + 1, 1, 33792, 0);
  }

#undef LOAD_BV
#undef STAGE_B
#undef LOAD_A2
#undef CT_BODY

  // epilogue: D[m=quad*4+r][n=lane&15], scale by demod[b,o], f32 out
  const int ob = mt * 128 + wm * 64;
  const int nb = nt * 128 + wn * 64;
#pragma unroll
  for (int ms = 0; ms < 4; ++ms)
#pragma unroll
    for (int ns = 0; ns < 4; ++ns) {
      const int n = nb + ns * 16 + m16;
#pragma unroll
      for (int r = 0; r < 4; ++r) {
        const int o = ob + ms * 16 + quad * 4 + r;
        float dm = demod_buf[b * 512 + o];
        out[((size_t)(b * 512 + o) << 12) + n] = acc[ms][ns][r] * dm;
      }
    }
}

// ---------------------------------------------------------------------------
extern "C" void kernel_launch(void* const* d_in, const int* in_sizes, int n_in,
                              void* d_out, int out_size, void* d_ws, size_t ws_size,
                              hipStream_t stream) {
  const float* input = (const float*)d_in[0];   // [8,512,64,64] f32
  const float* style = (const float*)d_in[1];   // [8,512] f32
  const float* weight = (const float*)d_in[2];  // [1,512,512,3,3] f32
  const float* modw = (const float*)d_in[3];    // [512,512] f32
  const float* modb = (const float*)d_in[4];    // [512] f32
  float* out = (float*)d_out;                   // [8,512,64,64] f32
  char* ws = (char*)d_ws;
  float* s_buf = (float*)ws;                             // 16 KB
  float* demod_buf = (float*)(ws + 16384);               // 16 KB
  float* ssq = (float*)(ws + 32768);                     // 1 MB
  u16* in_t = (u16*)(ws + 32768 + 1048576);              // NHWC bf16, 33.5 MB
  u16* w_t = (u16*)(ws + 32768 + 1048576 + 33554432);    // frag bf16, 4.7 MB

  k_prep1<<<dim3(2048), dim3(256), 0, stream>>>(style, modw, modb, weight, s_buf, ssq);
  k_fused2<<<dim3(5632), dim3(256), 0, stream>>>(input, s_buf, weight, ssq,
                                                 (unsigned*)in_t, (unsigned*)w_t,
                                                 demod_buf);
  k_conv<<<dim3(32, 4, 8), dim3(256), 0, stream>>>(in_t, w_t, demod_buf, out);
}

// Round 13
// 241.724 us; speedup vs baseline: 1.0681x; 1.0681x over previous
//
#include <hip/hip_runtime.h>

typedef unsigned short u16;
typedef __bf16 bf16_t;
typedef bf16_t bf16x8 __attribute__((ext_vector_type(8)));
typedef float floatx4 __attribute__((ext_vector_type(4)));

static constexpr float kScale = 0.014731391274719741f;    // 1/sqrt(512*9)
static constexpr float kScale2 = 2.1701388888888894e-4f;  // 1/(512*9)
static constexpr float kLinScale = 0.044194173824159216f; // 1/sqrt(512)

__device__ __forceinline__ u16 f2bf(float f) {
  unsigned u = __float_as_uint(f);
  u += 0x7FFFu + ((u >> 16) & 1u);
  return (u16)(u >> 16);
}

// async 16B global->LDS; LDS dst semantics: wave-uniform base + lane*16
#define GLD16(g, l)                                                        \
  __builtin_amdgcn_global_load_lds(                                        \
      (const __attribute__((address_space(1))) unsigned int*)(g),          \
      (__attribute__((address_space(3))) unsigned int*)(l), 16, 0, 0)

// ---------------------------------------------------------------------------
// Fused prep: blocks [0,1024): s[b,c] = style.modw^T*lin + bias
//             blocks [1024,2048): ssq[o,c] = sum_tap w^2
__global__ __launch_bounds__(256) void k_prep1(const float* __restrict__ style,
                                               const float* __restrict__ modw,
                                               const float* __restrict__ modb,
                                               const float* __restrict__ weight,
                                               float* __restrict__ s_buf,
                                               float* __restrict__ ssq) {
  int tid = threadIdx.x;
  if (blockIdx.x < 1024) {
    int lane = tid & 63, wv = tid >> 6;
    int idx = blockIdx.x * 4 + wv; // [0,4096)
    int b = idx >> 9, c = idx & 511;
    const float* st = style + b * 512;
    const float* mw = modw + (size_t)c * 512;
    float s = 0.f;
#pragma unroll
    for (int i = 0; i < 8; ++i) s += st[lane + i * 64] * mw[lane + i * 64];
#pragma unroll
    for (int off = 32; off; off >>= 1) s += __shfl_xor(s, off);
    if (lane == 0) s_buf[idx] = s * kLinScale + modb[c];
  } else {
    int e = (blockIdx.x - 1024) * 256 + tid; // [0, 262144)
    const float* wp = weight + (size_t)e * 9;
    float ss = 0.f;
#pragma unroll
    for (int t = 0; t < 9; ++t) ss += wp[t] * wp[t];
    ssq[e] = ss;
  }
}

// ---------------------------------------------------------------------------
// Fused stage 2 (one launch) — R10 version (scalar transpose is verified
// conflict-free; vectorized variant regressed):
//   blocks [0,4096):      NCHW f32 -> NHWC bf16 transpose with modulation
//   blocks [4096,4608):   weight fragment repack (batch-independent)
//   blocks [4608,5632):   demod[b,o] = rsqrt(kScale^2*sum ssq*s^2 + eps)
__global__ __launch_bounds__(256) void k_fused2(const float* __restrict__ in,
                                                const float* __restrict__ s_buf,
                                                const float* __restrict__ weight,
                                                const float* __restrict__ ssq,
                                                unsigned* __restrict__ in_t32,
                                                unsigned* __restrict__ wt32,
                                                float* __restrict__ demod_buf) {
  __shared__ char shm[9216];
  int tid = threadIdx.x;
  int bid = blockIdx.x;
  if (bid < 4096) {
    // ---- transpose: bid = c0g + 8*y + 512*b ----
    u16* tile = (u16*)shm; // [64*65] u16 = 8320 B
    int c0 = (bid & 7) * 64, y = (bid >> 3) & 63, b = bid >> 9;
    const float* src = in + ((size_t)(b * 512 + c0) * 4096) + y * 64;
    const float* srow = s_buf + b * 512 + c0;
#pragma unroll
    for (int it = 0; it < 16; ++it) {
      int idx = it * 256 + tid;
      int cl = idx >> 6, x = idx & 63;
      tile[cl * 65 + x] = f2bf(src[(size_t)cl * 4096 + x] * srow[cl]);
    }
    __syncthreads();
    unsigned* dst = in_t32 + ((size_t)(b * 64 + y) * 64) * 256 + (c0 >> 1);
#pragma unroll
    for (int it = 0; it < 8; ++it) {
      int flat = it * 256 + tid; // [0,2048)
      int cl2 = flat & 31, x = flat >> 5;
      unsigned lo = tile[(2 * cl2) * 65 + x];
      unsigned hi = tile[(2 * cl2 + 1) * 65 + x];
      dst[(size_t)x * 256 + cl2] = lo | (hi << 16);
    }
  } else if (bid < 4608) {
    // ---- wfrag: w = bid-4096; ct = w&15, ot = w>>4 ----
    u16(*tiles)[512] = (u16(*)[512])shm; // [9][512] u16 = 9216 B
    int w = bid - 4096;
    int ct = w & 15, ot = w >> 4;
    int o0 = ot * 16, c0 = ct * 32;
#pragma unroll
    for (int i = 0; i < 18; ++i) {
      int flat = i * 256 + tid;       // [0,4608) = o_l*288 + c_l*9 + tap
      int t9 = flat / 9;
      int tap = flat - t9 * 9;
      int o_l = t9 >> 5, c_l = t9 & 31;
      float wt = weight[((size_t)(o0 + o_l) * 512 + c0 + c_l) * 9 + tap];
      int pos = ((o_l + ((c_l >> 3) << 4)) << 3) + (c_l & 7);
      tiles[tap][pos] = f2bf(wt * kScale);
    }
    __syncthreads();
    const unsigned* tl = (const unsigned*)tiles;
#pragma unroll
    for (int tap = 0; tap < 9; ++tap)
      wt32[(size_t)((tap * 16 + ct) * 32 + ot) * 256 + tid] = tl[tap * 256 + tid];
  } else {
    // ---- demod: idx = (bid-4608)*4 + wave ----
    int lane = tid & 63, wv = tid >> 6;
    int idx = (bid - 4608) * 4 + wv; // [0,4096)
    int b = idx >> 9, o = idx & 511;
    const float* sq = ssq + (size_t)o * 512;
    const float* srow = s_buf + b * 512;
    float ss = 0.f;
#pragma unroll
    for (int i = 0; i < 8; ++i) {
      float s = srow[lane + i * 64];
      ss += sq[lane + i * 64] * s * s;
    }
#pragma unroll
    for (int off = 32; off; off >>= 1) ss += __shfl_xor(ss, off);
    if (lane == 0) demod_buf[idx] = rsqrtf(ss * kScale2 + 1e-8f);
  }
}

// ---------------------------------------------------------------------------
// Implicit-GEMM conv — R10 champion, restored byte-for-byte (127 us, 56%
// MfmaUtil, 0 bank conflicts, 0 spill).
// LOAD-BEARING DETAIL (R12 lesson): the s_setprio(1)/(0) pair around the
// MFMA cluster is NOT a priority optimization here — it is a side-effecting
// instruction the scheduler cannot move memory ops across, which keeps the
// depth-1 A/B register rings live (VGPR=128). Removing it let the pre-RA
// scheduler sink the prefetch loads to their uses (VGPR->96), exposing full
// load latency per t-step: 127 -> 159 us, MfmaUtil 56 -> 42%. DO NOT REMOVE.
// Structure: K=64 per t-step (2 k-halves), double-buffered 64-ch B cells,
// 64B-cell 8-slot swizzle slot=chunk8^(x&7) (conflict-free, verified),
// depth-1 A/B register rings, counted vmcnt(8) barrier (stage stays in
// flight across the t-loop), XCD swizzle lin&7 = batch (b-major optimal;
// mt-major regressed +10 MB FETCH).
__global__ __launch_bounds__(256, 2) void k_conv(const u16* __restrict__ in_t,
                                                 const u16* __restrict__ w_t,
                                                 const float* __restrict__ demod_buf,
                                                 float* __restrict__ out) {
  __shared__ char smem[67584]; // 2 buffers x (4 rows x 66 cells x 128 B)
  const int tid = threadIdx.x;
  const int lane = tid & 63;
  const int wv = tid >> 6;
  const int wm = wv >> 1, wn = wv & 1;
  const int quad = lane >> 4, m16 = lane & 15;
  const int lin = blockIdx.x + 32 * blockIdx.y + 128 * blockIdx.z; // [0,1024)
  const int b = lin & 7;
  const int r_ = lin >> 3;   // [0,128)
  const int nt = r_ & 31;
  const int mt = r_ >> 5;    // [0,4)
  const int y0 = nt * 2;

  floatx4 acc[4][4];
#pragma unroll
  for (int i = 0; i < 4; ++i)
#pragma unroll
    for (int j = 0; j < 4; ++j) acc[i][j] = (floatx4){0.f, 0.f, 0.f, 0.f};

  // per-lane A base (u16); A frag ms of (tap, ct32) at
  // abase + ((tap*16 + ct32)<<14) + ms*512, ct32 = 2*ct' + kh
  const u16* abase = w_t + mt * 4096 + wm * 2048 + lane * 8;

  // B stage source: thread covers slot chunk of cell xs (h=0: x 0..31;
  // h=1 adds +16384 u16 = +32 cells). Inverse swizzle on the source.
  const int xs = tid >> 3, qs = tid & 7;
  const int cch = qs ^ (xs & 7); // global 8-ch chunk stored at slot qs
  const u16* gB[4];
  bool rok[4];
#pragma unroll
  for (int r = 0; r < 4; ++r) {
    int y = y0 - 1 + r;
    rok[r] = (unsigned)y < 64u; // block-uniform
    gB[r] = in_t + (((size_t)(b * 64 + (rok[r] ? y : 0)) * 64 + xs) * 512 + cch * 8);
  }

  // B read bases, one per (dx, kh). row=(wn+dy):
  // addr = row*8448 + (sx+1)*128 + ((kh*4+quad)^(sx&7))*16,
  // sx = ns*16+m16+dx-1; ns-step = +2048 (slot invariant), dy-step = +8448.
  char* bA[6];
#pragma unroll
  for (int dx = 0; dx < 3; ++dx) {
    const int sx0 = m16 + dx - 1;
#pragma unroll
    for (int kh = 0; kh < 2; ++kh)
      bA[dx * 2 + kh] = smem + wn * 8448 + (sx0 + 1) * 128 +
                        (((kh * 4 + quad) ^ (sx0 & 7)) << 4);
  }

  bf16x8 aR[2][2][4];
  bf16x8 bv[2][2][4];

#define LOAD_BV(si, bufimm, t_)                                              \
  {                                                                          \
    const int dy_ = (t_) / 3, dx_ = (t_) % 3;                                \
    _Pragma("unroll") for (int kh = 0; kh < 2; ++kh)                         \
      _Pragma("unroll") for (int ns = 0; ns < 4; ++ns)                       \
        bv[si][kh][ns] = *(const bf16x8*)(bA[dx_ * 2 + kh] + (bufimm) +      \
                                          dy_ * 8448 + ns * 2048);           \
  }

#define STAGE_B(bufimm)                                                      \
  {                                                                          \
    _Pragma("unroll") for (int r = 0; r < 4; ++r)                            \
      if (rok[r]) {                                                          \
        GLD16(gB[r], smem + (bufimm) + r * 8448 + 128 + wv * 1024);          \
        GLD16(gB[r] + 16384,                                                 \
              smem + (bufimm) + r * 8448 + 128 + 4096 + wv * 1024);          \
      }                                                                      \
  }

#define LOAD_A2(si, tp_, ctp_)                                               \
  {                                                                          \
    _Pragma("unroll") for (int kh = 0; kh < 2; ++kh) {                       \
      const u16* ap_ =                                                       \
          abase + ((size_t)((tp_)*16 + 2 * (ctp_) + kh) << 14);              \
      _Pragma("unroll") for (int ms = 0; ms < 4; ++ms)                       \
        aR[si][kh][ms] = *(const bf16x8*)(ap_ + ms * 512);                   \
    }                                                                        \
  }

// one ct' (64 channels): 9 tap-steps of 32 MFMA; A+B frag prefetch depth 1;
// stage(ct'+1) in flight across the whole t-loop, drained by vmcnt(8).
#define CT_BODY(ctv, par, CURIMM, NXTIMM)                                    \
  {                                                                          \
    LOAD_BV(par, CURIMM, 0);                                                 \
    if ((ctv) + 1 < 8) {                                                     \
      _Pragma("unroll") for (int r = 0; r < 4; ++r) gB[r] += 64;             \
      STAGE_B(NXTIMM);                                                       \
    }                                                                        \
    _Pragma("unroll") for (int t = 0; t < 9; ++t) {                          \
      const int icur = (t + (par)) & 1;                                      \
      const int inxt = icur ^ 1;                                             \
      const int tp = t < 8 ? t + 1 : 0;                                      \
      const int ctp = t < 8 ? (ctv) : (ctv) + 1;                             \
      LOAD_A2(inxt, tp, ctp);                                                \
      if (t < 8) { LOAD_BV(inxt, CURIMM, t + 1); }                           \
      __builtin_amdgcn_s_setprio(1);                                         \
      _Pragma("unroll") for (int kh = 0; kh < 2; ++kh)                       \
        _Pragma("unroll") for (int ns = 0; ns < 4; ++ns)                     \
          _Pragma("unroll") for (int ms = 0; ms < 4; ++ms)                   \
            acc[ms][ns] = __builtin_amdgcn_mfma_f32_16x16x32_bf16(           \
                aR[icur][kh][ms], bv[icur][kh][ns], acc[ms][ns], 0, 0, 0);   \
      __builtin_amdgcn_s_setprio(0);                                         \
    }                                                                        \
    asm volatile("s_waitcnt vmcnt(8)" ::: "memory");                         \
    __builtin_amdgcn_s_barrier();                                            \
  }

  // ---- prologue: zero LDS (pads + OOB rows), stage ct'=0, load A(0, 0|1) --
  {
    const uint4 z = make_uint4(0u, 0u, 0u, 0u);
    for (int i = tid; i < 4224; i += 256) ((uint4*)smem)[i] = z;
  }
  __syncthreads();
  STAGE_B(0);
  __syncthreads(); // drains stage(0) + makes zeros visible
  LOAD_A2(0, 0, 0);

  for (int ct = 0; ct < 8; ct += 2) {
    CT_BODY(ct, 0, 0, 33792);
    CT_BODY(ct + 1, 1, 33792, 0);
  }

#undef LOAD_BV
#undef STAGE_B
#undef LOAD_A2
#undef CT_BODY

  // epilogue: D[m=quad*4+r][n=lane&15], scale by demod[b,o], f32 out
  const int ob = mt * 128 + wm * 64;
  const int nb = nt * 128 + wn * 64;
#pragma unroll
  for (int ms = 0; ms < 4; ++ms)
#pragma unroll
    for (int ns = 0; ns < 4; ++ns) {
      const int n = nb + ns * 16 + m16;
#pragma unroll
      for (int r = 0; r < 4; ++r) {
        const int o = ob + ms * 16 + quad * 4 + r;
        float dm = demod_buf[b * 512 + o];
        out[((size_t)(b * 512 + o) << 12) + n] = acc[ms][ns][r] * dm;
      }
    }
}

// ---------------------------------------------------------------------------
extern "C" void kernel_launch(void* const* d_in, const int* in_sizes, int n_in,
                              void* d_out, int out_size, void* d_ws, size_t ws_size,
                              hipStream_t stream) {
  const float* input = (const float*)d_in[0];   // [8,512,64,64] f32
  const float* style = (const float*)d_in[1];   // [8,512] f32
  const float* weight = (const float*)d_in[2];  // [1,512,512,3,3] f32
  const float* modw = (const float*)d_in[3];    // [512,512] f32
  const float* modb = (const float*)d_in[4];    // [512] f32
  float* out = (float*)d_out;                   // [8,512,64,64] f32
  char* ws = (char*)d_ws;
  float* s_buf = (float*)ws;                             // 16 KB
  float* demod_buf = (float*)(ws + 16384);               // 16 KB
  float* ssq = (float*)(ws + 32768);                     // 1 MB
  u16* in_t = (u16*)(ws + 32768 + 1048576);              // NHWC bf16, 33.5 MB
  u16* w_t = (u16*)(ws + 32768 + 1048576 + 33554432);    // frag bf16, 4.7 MB

  k_prep1<<<dim3(2048), dim3(256), 0, stream>>>(style, modw, modb, weight, s_buf, ssq);
  k_fused2<<<dim3(5632), dim3(256), 0, stream>>>(input, s_buf, weight, ssq,
                                                 (unsigned*)in_t, (unsigned*)w_t,
                                                 demod_buf);
  k_conv<<<dim3(32, 4, 8), dim3(256), 0, stream>>>(in_t, w_t, demod_buf, out);
}